// Round 5
// baseline (458.219 us; speedup 1.0000x reference)
//
#include <hip/hip_runtime.h>

// GRUObservationCellLogvar — R5: 1-wave independent blocks, fine-grain het fusion.
// N=500000, N_OBS=200000, D=32, H=128, P=4
// out = [ h_updated (500000*128) | losses (200000*32) ] fp32
//
// k_prepack: W -> bf16 B-fragments (ws, 192 KB), grouped by col-group cg:
//            frag f layout per cg: 0-7 R(k0..255), 8-15 Z, 16-19 IN(k<128), 20-23 HN(k>=128)
// k_flag:    flags[i_obs[i]] = 1  (after memsetAsync 0)
// k_het:     64-thread blocks. bid%4==3 -> copy role (8192 float4 span, flag-gated,
//            unobserved rows only). else -> main role: 32 rows, single wave:
//            shfl-distributed indices, early gathers, LDS A-fragment staging,
//            A in VGPRs, cg-loop with B reload from L2, fast-math GRU epilogue.
// Disjoint write sets (flags) => race-free.

typedef __attribute__((ext_vector_type(8))) short bf16x8;
typedef __attribute__((ext_vector_type(4))) float f32x4;

__device__ inline unsigned short f2bf_rne(float x) {
    union { float f; unsigned int u; } v; v.f = x;
    unsigned int r = (v.u + 0x7fffu + ((v.u >> 16) & 1u)) >> 16;
    return (unsigned short)r;
}
__device__ inline unsigned short f2bf_tr(float x) {
    return (unsigned short)(__float_as_uint(x) >> 16);
}
__device__ inline float bf2f(unsigned short u) {
    return __uint_as_float(((unsigned int)u) << 16);
}
__device__ inline float fast_sigmoid(float x) {
    return __builtin_amdgcn_rcpf(1.f + __expf(-x));
}
__device__ inline float fast_tanh(float x) {
    const float a = fabsf(x);
    const float t = __expf(-2.f * a);
    const float r = (1.f - t) * __builtin_amdgcn_rcpf(1.f + t);
    return __builtin_copysignf(r, x);
}

// ---- B prepack: 98304 bf16 = 8 cg * 24 frags * 64 lanes * 8 (RNE) ----
__global__ __launch_bounds__(256) void k_prepack(const float* __restrict__ W_ih,
                                                 const float* __restrict__ W_hh,
                                                 unsigned short* __restrict__ B) {
    const int i = blockIdx.x * 256 + threadIdx.x;
    const int w    = i / 12288;
    const int rem  = i - w * 12288;
    const int f    = rem >> 9;
    const int rem2 = rem & 511;
    const int l    = rem2 >> 3;
    const int j    = rem2 & 7;
    const int c    = w * 16 + (l & 15);
    const int ko   = (l >> 4) * 8 + j;
    float val;
    if (f < 8) {
        const int k = f * 32 + ko;
        val = (k < 128) ? W_ih[c * 128 + k] : W_hh[c * 128 + (k - 128)];
    } else if (f < 16) {
        const int k = (f - 8) * 32 + ko;
        val = (k < 128) ? W_ih[(128 + c) * 128 + k] : W_hh[(128 + c) * 128 + (k - 128)];
    } else if (f < 20) {
        const int k = (f - 16) * 32 + ko;
        val = W_ih[(256 + c) * 128 + k];
    } else {
        const int k = (f - 20 + 4) * 32 + ko;
        val = W_hh[(256 + c) * 128 + (k - 128)];
    }
    B[i] = f2bf_rne(val);
}

__global__ __launch_bounds__(256) void k_flag(const int* __restrict__ i_obs,
                                              unsigned char* __restrict__ flags, int n) {
    const int i = blockIdx.x * 256 + threadIdx.x;
    if (i < n) flags[i_obs[i]] = 1;
}

// fallback full copy
__global__ __launch_bounds__(256) void k_copy(const float4* __restrict__ src,
                                              float4* __restrict__ dst, long n4) {
    long i = (long)blockIdx.x * blockDim.x + threadIdx.x;
    long stride = (long)gridDim.x * blockDim.x;
    for (; i < n4; i += stride) dst[i] = src[i];
}

// ---------------- main role: one wave, 32 rows ----------------
__device__ __forceinline__ void main_role(int mbid,
    const float* __restrict__ h, const float* __restrict__ p,
    const float* __restrict__ X_obs, const float* __restrict__ M_obs,
    const int* __restrict__ i_obs,
    const float* __restrict__ w_prep, const float* __restrict__ bias_prep,
    const unsigned short* __restrict__ Bpk,
    const float* __restrict__ b_ih, const float* __restrict__ b_hh,
    float* __restrict__ out_h, float* __restrict__ out_losses,
    unsigned short* sA)
{
    const int lane = threadIdx.x;      // 0..63
    const int row0 = mbid * 32;
    const int myidx = i_obs[row0 + (lane & 31)];

    // ---- prep: losses + gru_in fragments (rows 0..31, d = lane&31) ----
    {
        const int d = lane & 31;
        float wp[16], bp[4];
        #pragma unroll
        for (int t = 0; t < 16; ++t) wp[t] = w_prep[d * 16 + t];
        #pragma unroll
        for (int t = 0; t < 4; ++t) bp[t] = bias_prep[d * 4 + t];

        const int ksA   = d >> 3;
        const int l16A  = ((d >> 1) & 3) * 16;
        const int j0A   = (d & 1) * 4;

        #pragma unroll
        for (int pass = 0; pass < 16; ++pass) {
            const int r   = pass * 2 + (lane >> 5);
            const int idx = __shfl(myidx, r);
            const float mean   = p[(size_t)idx * 64 + d];
            const float logvar = p[(size_t)idx * 64 + 32 + d];
            const float X = X_obs[(size_t)(row0 + r) * 32 + d];
            const float M = M_obs[(size_t)(row0 + r) * 32 + d];
            const float lv      = fminf(fmaxf(logvar, -10.f), 10.f);
            const float inv_sig = __expf(-0.5f * lv);
            const float err     = fminf(fmaxf((X - mean) * inv_sig, -1e6f), 1e6f);
            out_losses[(size_t)(row0 + r) * 32 + d] =
                0.5f * ((err * err + lv + 1.8378770664093453f) * M);
            ushort4 u;
            float g0 = fmaf(X, wp[0], fmaf(mean, wp[4], fmaf(lv, wp[8],  fmaf(err, wp[12], bp[0]))));
            float g1 = fmaf(X, wp[1], fmaf(mean, wp[5], fmaf(lv, wp[9],  fmaf(err, wp[13], bp[1]))));
            float g2 = fmaf(X, wp[2], fmaf(mean, wp[6], fmaf(lv, wp[10], fmaf(err, wp[14], bp[2]))));
            float g3 = fmaf(X, wp[3], fmaf(mean, wp[7], fmaf(lv, wp[11], fmaf(err, wp[15], bp[3]))));
            u.x = f2bf_tr(fmaxf(g0, 0.f) * M);
            u.y = f2bf_tr(fmaxf(g1, 0.f) * M);
            u.z = f2bf_tr(fmaxf(g2, 0.f) * M);
            u.w = f2bf_tr(fmaxf(g3, 0.f) * M);
            const int mt = r >> 4;
            *reinterpret_cast<ushort4*>(&sA[((mt * 8 + ksA) * 64 + (r & 15) + l16A) * 8 + j0A]) = u;
        }

        // h gather: c4 = lane&31, k = 128 + c4*4
        const int c4   = lane & 31;
        const int ksH  = 4 + (c4 >> 3);
        const int l16H = ((c4 >> 1) & 3) * 16;
        const int j0H  = (c4 & 1) * 4;
        #pragma unroll
        for (int pass = 0; pass < 16; ++pass) {
            const int r   = pass * 2 + (lane >> 5);
            const int idx = __shfl(myidx, r);
            const float4 v = *reinterpret_cast<const float4*>(h + (size_t)idx * 128 + c4 * 4);
            ushort4 u;
            u.x = f2bf_tr(v.x); u.y = f2bf_tr(v.y); u.z = f2bf_tr(v.z); u.w = f2bf_tr(v.w);
            const int mt = r >> 4;
            *reinterpret_cast<ushort4*>(&sA[((mt * 8 + ksH) * 64 + (r & 15) + l16H) * 8 + j0H]) = u;
        }
    }
    __syncthreads();   // single wave: compiles to waitcnt (+ cheap barrier)

    // ---- A fragments into registers: 2 mt x 8 ks ----
    bf16x8 areg[16];
    {
        const bf16x8* ap = reinterpret_cast<const bf16x8*>(sA);
        #pragma unroll
        for (int t = 0; t < 16; ++t) areg[t] = ap[t * 64 + lane];
    }

    // ---- column-group loop ----
    #pragma unroll 1
    for (int cg = 0; cg < 8; ++cg) {
        const int c = cg * 16 + (lane & 15);

        bf16x8 breg[24];
        const bf16x8* bsrc = reinterpret_cast<const bf16x8*>(Bpk) + cg * 1536;
        #pragma unroll
        for (int f = 0; f < 24; ++f) breg[f] = bsrc[f * 64 + lane];

        const float bR  = b_ih[c]       + b_hh[c];
        const float bZ  = b_ih[128 + c] + b_hh[128 + c];
        const float bIN = b_ih[256 + c];
        const float bHN = b_hh[256 + c];

        // epilogue h_old coords (k = 128 + c)
        const int ksE  = 4 + (cg >> 1);
        const int l16E = ((c >> 3) & 3) * 16;
        const int jE   = c & 7;

        #pragma unroll
        for (int mt = 0; mt < 2; ++mt) {
            f32x4 accR = {0.f, 0.f, 0.f, 0.f};
            f32x4 accZ = {0.f, 0.f, 0.f, 0.f};
            f32x4 accIN = {0.f, 0.f, 0.f, 0.f};
            f32x4 accHN = {0.f, 0.f, 0.f, 0.f};
            #pragma unroll
            for (int ks = 0; ks < 8; ++ks) {
                const bf16x8 af = areg[mt * 8 + ks];
                accR = __builtin_amdgcn_mfma_f32_16x16x32_bf16(af, breg[ks],     accR, 0, 0, 0);
                accZ = __builtin_amdgcn_mfma_f32_16x16x32_bf16(af, breg[8 + ks], accZ, 0, 0, 0);
                if (ks < 4) accIN = __builtin_amdgcn_mfma_f32_16x16x32_bf16(af, breg[16 + ks], accIN, 0, 0, 0);
                else        accHN = __builtin_amdgcn_mfma_f32_16x16x32_bf16(af, breg[16 + ks], accHN, 0, 0, 0);
            }
            const int r15b = (lane >> 4) * 4;
            #pragma unroll
            for (int reg = 0; reg < 4; ++reg) {
                const int r15 = r15b + reg;
                const int idx = __shfl(myidx, mt * 16 + r15);
                const float hp = bf2f(sA[((mt * 8 + ksE) * 64 + r15 + l16E) * 8 + jE]);
                const float xr  = accR[reg]  + bR;
                const float xz  = accZ[reg]  + bZ;
                const float xin = accIN[reg] + bIN;
                const float xhn = accHN[reg] + bHN;
                const float rg = fast_sigmoid(xr);
                const float zg = fast_sigmoid(xz);
                const float ng = fast_tanh(fmaf(rg, xhn, xin));
                out_h[(size_t)idx * 128 + c] = fmaf(zg, hp - ng, ng);
            }
        }
    }
}

// ---------------- copy role: 8192-float4 span, unobserved rows only ----------------
__device__ __forceinline__ void copy_role(int cbid,
    const float4* __restrict__ src, float4* __restrict__ dst,
    const unsigned char* __restrict__ flags, long n4)
{
    const long base = (long)cbid * 8192;
    #pragma unroll 8
    for (int it = 0; it < 128; ++it) {
        const long i = base + (long)it * 64 + threadIdx.x;
        if (i < n4) {
            const int row = (int)(i >> 5);
            if (!flags[row]) dst[i] = src[i];
        }
    }
}

__global__ __launch_bounds__(64) void k_het(
    const float* __restrict__ h, const float* __restrict__ p,
    const float* __restrict__ X_obs, const float* __restrict__ M_obs,
    const int* __restrict__ i_obs,
    const float* __restrict__ w_prep, const float* __restrict__ bias_prep,
    const unsigned short* __restrict__ Bpk,
    const float* __restrict__ b_ih, const float* __restrict__ b_hh,
    float* __restrict__ out_h, float* __restrict__ out_losses,
    const unsigned char* __restrict__ flags, long n4, int nmain, int ncopy)
{
    __shared__ unsigned short sA[2 * 8 * 64 * 8];   // 16 KB (one wave's A frags)

    const int bid = blockIdx.x;
    if (ncopy > 0) {
        const int r = bid & 3;
        const int g = bid >> 2;
        if (r == 3) {
            if (g < ncopy)
                copy_role(g, (const float4*)h, (float4*)out_h, flags, n4);
            return;
        }
        const int mbid = g * 3 + r;
        if (mbid >= nmain) return;
        main_role(mbid, h, p, X_obs, M_obs, i_obs, w_prep, bias_prep,
                  Bpk, b_ih, b_hh, out_h, out_losses, sA);
    } else {
        if (bid < nmain)
            main_role(bid, h, p, X_obs, M_obs, i_obs, w_prep, bias_prep,
                      Bpk, b_ih, b_hh, out_h, out_losses, sA);
    }
}

extern "C" void kernel_launch(void* const* d_in, const int* in_sizes, int n_in,
                              void* d_out, int out_size, void* d_ws, size_t ws_size,
                              hipStream_t stream) {
    const float* h         = (const float*)d_in[0];
    const float* p         = (const float*)d_in[1];
    const float* X_obs     = (const float*)d_in[2];
    const float* M_obs     = (const float*)d_in[3];
    const int*   i_obs     = (const int*)d_in[4];
    const float* w_prep    = (const float*)d_in[5];
    const float* bias_prep = (const float*)d_in[6];
    const float* W_ih      = (const float*)d_in[7];
    const float* W_hh      = (const float*)d_in[8];
    const float* b_ih      = (const float*)d_in[9];
    const float* b_hh      = (const float*)d_in[10];

    const int Nh    = in_sizes[0] / 128;    // 500000
    const int NOBS  = in_sizes[4];          // 200000
    const int NMAIN = NOBS / 32;            // 6250
    const long n4   = (long)Nh * 128 / 4;   // 16M float4

    float* out_h      = (float*)d_out;
    float* out_losses = out_h + (size_t)Nh * 128;

    unsigned short* Bpk   = (unsigned short*)d_ws;               // 192 KB
    unsigned char*  flags = (unsigned char*)d_ws + (256 << 10);  // Nh bytes
    const size_t ws_needed = (256 << 10) + (size_t)Nh;

    hipLaunchKernelGGL(k_prepack, dim3(98304 / 256), dim3(256), 0, stream,
                       W_ih, W_hh, Bpk);

    if (ws_size >= ws_needed) {
        hipMemsetAsync(flags, 0, (size_t)Nh, stream);
        hipLaunchKernelGGL(k_flag, dim3((NOBS + 255) / 256), dim3(256), 0, stream,
                           i_obs, flags, NOBS);
        const int NCOPY  = (int)((n4 + 8191) / 8192);            // 2048
        const int rounds = (NMAIN + 2) / 3;                      // 2084
        const int rnds   = rounds > NCOPY ? rounds : NCOPY;
        const int grid   = rnds * 4;
        hipLaunchKernelGGL(k_het, dim3(grid), dim3(64), 0, stream,
                           h, p, X_obs, M_obs, i_obs, w_prep, bias_prep, Bpk,
                           b_ih, b_hh, out_h, out_losses, flags, n4, NMAIN, NCOPY);
    } else {
        hipLaunchKernelGGL(k_copy, dim3(4096), dim3(256), 0, stream,
                           (const float4*)h, (float4*)out_h, n4);
        hipLaunchKernelGGL(k_het, dim3(NMAIN), dim3(64), 0, stream,
                           h, p, X_obs, M_obs, i_obs, w_prep, bias_prep, Bpk,
                           b_ih, b_hh, out_h, out_losses,
                           (const unsigned char*)nullptr, n4, NMAIN, 0);
    }
}

// Round 6
// 250.930 us; speedup vs baseline: 1.8261x; 1.8261x over previous
//
#include <hip/hip_runtime.h>

// GRUObservationCellLogvar — R6: ILP-fused copy + GRU in one block.
// N=500000, N_OBS=200000, D=32, H=128, P=4
// out = [ h_updated (500000*128) | losses (200000*32) ] fp32
//
// Block b (512 thr): copies h-chunk [160b,160b+160) -> out_h (flag-gated stores,
// loads unconditional to warm L1/L2), then prep (losses + bf16 A-frags in LDS)
// for obs rows [64b,64b+64), then 8-wave MFMA dual-GEMM + fast-math GRU epilogue,
// scatter to out_h. Sorted i_obs => block's obs rows mostly inside its own chunk
// => h read from HBM exactly once. Disjoint write sets via flags => race-free.

typedef __attribute__((ext_vector_type(8))) short bf16x8;
typedef __attribute__((ext_vector_type(4))) float f32x4;

__device__ inline unsigned short f2bf_rne(float x) {
    union { float f; unsigned int u; } v; v.f = x;
    unsigned int r = (v.u + 0x7fffu + ((v.u >> 16) & 1u)) >> 16;
    return (unsigned short)r;
}
__device__ inline unsigned short f2bf_tr(float x) {
    return (unsigned short)(__float_as_uint(x) >> 16);
}
__device__ inline float bf2f(unsigned short u) {
    return __uint_as_float(((unsigned int)u) << 16);
}
__device__ inline float fast_sigmoid(float x) {
    return __builtin_amdgcn_rcpf(1.f + __expf(-x));
}
__device__ inline float fast_tanh(float x) {
    const float a = fabsf(x);
    const float t = __expf(-2.f * a);
    const float r = (1.f - t) * __builtin_amdgcn_rcpf(1.f + t);
    return __builtin_copysignf(r, x);
}

// ---- B prepack: 98304 bf16 = 8 cg * 24 frags * 64 lanes * 8 (RNE) ----
__global__ __launch_bounds__(256) void k_prepack(const float* __restrict__ W_ih,
                                                 const float* __restrict__ W_hh,
                                                 unsigned short* __restrict__ B) {
    const int i = blockIdx.x * 256 + threadIdx.x;
    const int w    = i / 12288;
    const int rem  = i - w * 12288;
    const int f    = rem >> 9;
    const int rem2 = rem & 511;
    const int l    = rem2 >> 3;
    const int j    = rem2 & 7;
    const int c    = w * 16 + (l & 15);
    const int ko   = (l >> 4) * 8 + j;
    float val;
    if (f < 8) {
        const int k = f * 32 + ko;
        val = (k < 128) ? W_ih[c * 128 + k] : W_hh[c * 128 + (k - 128)];
    } else if (f < 16) {
        const int k = (f - 8) * 32 + ko;
        val = (k < 128) ? W_ih[(128 + c) * 128 + k] : W_hh[(128 + c) * 128 + (k - 128)];
    } else if (f < 20) {
        const int k = (f - 16) * 32 + ko;
        val = W_ih[(256 + c) * 128 + k];
    } else {
        const int k = (f - 20 + 4) * 32 + ko;
        val = W_hh[(256 + c) * 128 + (k - 128)];
    }
    B[i] = f2bf_rne(val);
}

__global__ __launch_bounds__(256) void k_flag(const int* __restrict__ i_obs,
                                              unsigned char* __restrict__ flags, int n) {
    const int i = blockIdx.x * 256 + threadIdx.x;
    if (i < n) flags[i_obs[i]] = 1;
}

// fallback full copy (only used if ws too small for flags)
__global__ __launch_bounds__(256) void k_copy(const float4* __restrict__ src,
                                              float4* __restrict__ dst, long n4) {
    long i = (long)blockIdx.x * blockDim.x + threadIdx.x;
    long stride = (long)gridDim.x * blockDim.x;
    for (; i < n4; i += stride) dst[i] = src[i];
}

__global__ __launch_bounds__(512) void k_fused(
    const float* __restrict__ h, const float* __restrict__ p,
    const float* __restrict__ X_obs, const float* __restrict__ M_obs,
    const int* __restrict__ i_obs,
    const float* __restrict__ w_prep, const float* __restrict__ bias_prep,
    const unsigned short* __restrict__ Bpk,
    const float* __restrict__ b_ih, const float* __restrict__ b_hh,
    float* __restrict__ out_h, float* __restrict__ out_losses,
    const unsigned char* __restrict__ flags,
    int chunk_rows, int Nh, int do_copy)
{
    __shared__ unsigned short sA[4 * 8 * 64 * 8];   // 32 KB
    __shared__ int sIdx[64];

    const int tid  = threadIdx.x;
    const int bid  = blockIdx.x;
    const int row0 = bid * 64;

    if (tid < 64) sIdx[tid] = i_obs[row0 + tid];

    // ---- ILP-fused copy of own h-chunk (warms L1/L2 for the gather) ----
    if (do_copy) {
        const long rlo  = (long)bid * chunk_rows;
        long rhi = rlo + chunk_rows; if (rhi > Nh) rhi = Nh;
        const int nf4   = (int)((rhi - rlo) * 32);          // float4 count
        const float4* hsrc = reinterpret_cast<const float4*>(h + rlo * 128);
        float4*       hdst = reinterpret_cast<float4*>(out_h + rlo * 128);
        const unsigned char* fl = flags + rlo;
        #pragma unroll
        for (int pass = 0; pass < 10; ++pass) {
            const int i = pass * 512 + tid;
            if (i < nf4) {
                const float4 v = hsrc[i];                    // unconditional: warm cache
                if (!fl[i >> 5]) hdst[i] = v;                // gated: race-free
            }
        }
    }
    __syncthreads();

    // ---- prep: losses + gru_in bf16 frags ; h gather -> bf16 frags ----
    {
        const int d = tid & 31;
        float wp[16], bp[4];
        #pragma unroll
        for (int t = 0; t < 16; ++t) wp[t] = w_prep[d * 16 + t];
        #pragma unroll
        for (int t = 0; t < 4; ++t) bp[t] = bias_prep[d * 4 + t];

        const int ksA  = d >> 3;
        const int l16A = ((d >> 1) & 3) * 16;
        const int j0A  = (d & 1) * 4;

        #pragma unroll
        for (int pass = 0; pass < 4; ++pass) {
            const int r   = pass * 16 + (tid >> 5);
            const int row = row0 + r;
            const int idx = sIdx[r];
            const float mean   = p[(size_t)idx * 64 + d];
            const float logvar = p[(size_t)idx * 64 + 32 + d];
            const float X = X_obs[(size_t)row * 32 + d];
            const float M = M_obs[(size_t)row * 32 + d];
            const float lv      = fminf(fmaxf(logvar, -10.f), 10.f);
            const float inv_sig = __expf(-0.5f * lv);        // 1/sigma (clips inactive)
            const float err     = fminf(fmaxf((X - mean) * inv_sig, -1e6f), 1e6f);
            out_losses[(size_t)row * 32 + d] =
                0.5f * ((err * err + lv + 1.8378770664093453f) * M);
            ushort4 u;
            float g0 = fmaf(X, wp[0], fmaf(mean, wp[4], fmaf(lv, wp[8],  fmaf(err, wp[12], bp[0]))));
            float g1 = fmaf(X, wp[1], fmaf(mean, wp[5], fmaf(lv, wp[9],  fmaf(err, wp[13], bp[1]))));
            float g2 = fmaf(X, wp[2], fmaf(mean, wp[6], fmaf(lv, wp[10], fmaf(err, wp[14], bp[2]))));
            float g3 = fmaf(X, wp[3], fmaf(mean, wp[7], fmaf(lv, wp[11], fmaf(err, wp[15], bp[3]))));
            u.x = f2bf_tr(fmaxf(g0, 0.f) * M);
            u.y = f2bf_tr(fmaxf(g1, 0.f) * M);
            u.z = f2bf_tr(fmaxf(g2, 0.f) * M);
            u.w = f2bf_tr(fmaxf(g3, 0.f) * M);
            const int mt = r >> 4;
            *reinterpret_cast<ushort4*>(&sA[((mt * 8 + ksA) * 64 + (r & 15) + l16A) * 8 + j0A]) = u;
        }

        const int c4   = tid & 31;
        const int ksH  = 4 + (c4 >> 3);
        const int l16H = ((c4 >> 1) & 3) * 16;
        const int j0H  = (c4 & 1) * 4;
        #pragma unroll
        for (int pass = 0; pass < 4; ++pass) {
            const int r = pass * 16 + (tid >> 5);
            const float4 v = *reinterpret_cast<const float4*>(h + (size_t)sIdx[r] * 128 + c4 * 4);
            ushort4 u;
            u.x = f2bf_tr(v.x); u.y = f2bf_tr(v.y); u.z = f2bf_tr(v.z); u.w = f2bf_tr(v.w);
            const int mt = r >> 4;
            *reinterpret_cast<ushort4*>(&sA[((mt * 8 + ksH) * 64 + (r & 15) + l16H) * 8 + j0H]) = u;
        }
    }
    __syncthreads();

    // ---- MFMA phase: wave wid owns cols c = wid*16 + (lane&15) ----
    const int wid  = tid >> 6;
    const int lane = tid & 63;
    const int c    = wid * 16 + (lane & 15);

    bf16x8 breg[24];
    const bf16x8* bsrc = reinterpret_cast<const bf16x8*>(Bpk) + wid * 1536;
    #pragma unroll
    for (int f = 0; f < 24; ++f) breg[f] = bsrc[f * 64 + lane];

    const float bR  = b_ih[c]       + b_hh[c];
    const float bZ  = b_ih[128 + c] + b_hh[128 + c];
    const float bIN = b_ih[256 + c];
    const float bHN = b_hh[256 + c];

    const bf16x8* aptr = reinterpret_cast<const bf16x8*>(sA);
    const int ksE  = 4 + (c >> 5);           // epilogue h_old coords (k = 128+c)
    const int l16E = ((c >> 3) & 3) * 16;
    const int jE   = c & 7;

    #pragma unroll
    for (int mt = 0; mt < 4; ++mt) {
        f32x4 accR = {0.f, 0.f, 0.f, 0.f};
        f32x4 accZ = {0.f, 0.f, 0.f, 0.f};
        f32x4 accIN = {0.f, 0.f, 0.f, 0.f};
        f32x4 accHN = {0.f, 0.f, 0.f, 0.f};
        #pragma unroll
        for (int ks = 0; ks < 8; ++ks) {
            const bf16x8 af = aptr[(mt * 8 + ks) * 64 + lane];
            accR = __builtin_amdgcn_mfma_f32_16x16x32_bf16(af, breg[ks],     accR, 0, 0, 0);
            accZ = __builtin_amdgcn_mfma_f32_16x16x32_bf16(af, breg[8 + ks], accZ, 0, 0, 0);
            if (ks < 4) accIN = __builtin_amdgcn_mfma_f32_16x16x32_bf16(af, breg[16 + ks], accIN, 0, 0, 0);
            else        accHN = __builtin_amdgcn_mfma_f32_16x16x32_bf16(af, breg[16 + ks], accHN, 0, 0, 0);
        }
        const int r15b = (lane >> 4) * 4;
        #pragma unroll
        for (int reg = 0; reg < 4; ++reg) {
            const int r15 = r15b + reg;
            const int idx = sIdx[mt * 16 + r15];
            const float hp = bf2f(sA[((mt * 8 + ksE) * 64 + r15 + l16E) * 8 + jE]);
            const float xr  = accR[reg]  + bR;
            const float xz  = accZ[reg]  + bZ;
            const float xin = accIN[reg] + bIN;
            const float xhn = accHN[reg] + bHN;
            const float rg = fast_sigmoid(xr);
            const float zg = fast_sigmoid(xz);
            const float ng = fast_tanh(fmaf(rg, xhn, xin));
            out_h[(size_t)idx * 128 + c] = fmaf(zg, hp - ng, ng);
        }
    }
}

extern "C" void kernel_launch(void* const* d_in, const int* in_sizes, int n_in,
                              void* d_out, int out_size, void* d_ws, size_t ws_size,
                              hipStream_t stream) {
    const float* h         = (const float*)d_in[0];
    const float* p         = (const float*)d_in[1];
    const float* X_obs     = (const float*)d_in[2];
    const float* M_obs     = (const float*)d_in[3];
    const int*   i_obs     = (const int*)d_in[4];
    const float* w_prep    = (const float*)d_in[5];
    const float* bias_prep = (const float*)d_in[6];
    const float* W_ih      = (const float*)d_in[7];
    const float* W_hh      = (const float*)d_in[8];
    const float* b_ih      = (const float*)d_in[9];
    const float* b_hh      = (const float*)d_in[10];

    const int Nh   = in_sizes[0] / 128;   // 500000
    const int NOBS = in_sizes[4];         // 200000
    const int NT   = NOBS / 64;           // 3125 blocks
    const long n4  = (long)Nh * 128 / 4;

    float* out_h      = (float*)d_out;
    float* out_losses = out_h + (size_t)Nh * 128;

    unsigned short* Bpk   = (unsigned short*)d_ws;               // 192 KB
    unsigned char*  flags = (unsigned char*)d_ws + (256 << 10);  // Nh bytes
    const size_t ws_needed = (256 << 10) + (size_t)Nh;

    hipLaunchKernelGGL(k_prepack, dim3(98304 / 256), dim3(256), 0, stream,
                       W_ih, W_hh, Bpk);

    const int chunk = (Nh + NT - 1) / NT;    // 160 (<=160*32=5120 f4 => 10 passes)

    if (ws_size >= ws_needed && chunk <= 160) {
        hipMemsetAsync(flags, 0, (size_t)Nh, stream);
        hipLaunchKernelGGL(k_flag, dim3((NOBS + 255) / 256), dim3(256), 0, stream,
                           i_obs, flags, NOBS);
        hipLaunchKernelGGL(k_fused, dim3(NT), dim3(512), 0, stream,
                           h, p, X_obs, M_obs, i_obs, w_prep, bias_prep, Bpk,
                           b_ih, b_hh, out_h, out_losses, flags, chunk, Nh, 1);
    } else {
        hipLaunchKernelGGL(k_copy, dim3(4096), dim3(256), 0, stream,
                           (const float4*)h, (float4*)out_h, n4);
        hipLaunchKernelGGL(k_fused, dim3(NT), dim3(512), 0, stream,
                           h, p, X_obs, M_obs, i_obs, w_prep, bias_prep, Bpk,
                           b_ih, b_hh, out_h, out_losses,
                           (const unsigned char*)nullptr, chunk, Nh, 0);
    }
}

// Round 8
// 228.407 us; speedup vs baseline: 2.0062x; 1.0986x over previous
//
#include <hip/hip_runtime.h>

// GRUObservationCellLogvar — R8: persistent blocks + software-pipelined tiles.
// (R7 with the nontemporal-store compile fix: native ext_vector float4.)
// N=500000, N_OBS=200000, D=32, H=128, P=4
// out = [ h_updated (500000*128) | losses (200000*32) ] fp32
//
// k_pers (512 thr, grid 512, grid-stride over 3125 tiles):
//   pipeline per tile: G(t+1) gather->regs ; M(t) MFMA+GRU epilogue ; COPY(t)
//   chunk copy ; barrier ; C(t+1) pack->LDS ; barrier.
//   B-fragments (96 VGPR) resident via __launch_bounds__(512,2).
// Disjoint write sets via flags => copy/epilogue race-free.

typedef __attribute__((ext_vector_type(8))) short bf16x8;
typedef __attribute__((ext_vector_type(4))) float f32x4;

__device__ inline unsigned short f2bf_rne(float x) {
    union { float f; unsigned int u; } v; v.f = x;
    unsigned int r = (v.u + 0x7fffu + ((v.u >> 16) & 1u)) >> 16;
    return (unsigned short)r;
}
__device__ inline unsigned short f2bf_tr(float x) {
    return (unsigned short)(__float_as_uint(x) >> 16);
}
__device__ inline float bf2f(unsigned short u) {
    return __uint_as_float(((unsigned int)u) << 16);
}
__device__ inline float fast_sigmoid(float x) {
    return __builtin_amdgcn_rcpf(1.f + __expf(-x));
}
__device__ inline float fast_tanh(float x) {
    const float a = fabsf(x);
    const float t = __expf(-2.f * a);
    const float r = (1.f - t) * __builtin_amdgcn_rcpf(1.f + t);
    return __builtin_copysignf(r, x);
}

// ---- B prepack: 98304 bf16 = 8 cg * 24 frags * 64 lanes * 8 (RNE) ----
__global__ __launch_bounds__(256) void k_prepack(const float* __restrict__ W_ih,
                                                 const float* __restrict__ W_hh,
                                                 unsigned short* __restrict__ B) {
    const int i = blockIdx.x * 256 + threadIdx.x;
    const int w    = i / 12288;
    const int rem  = i - w * 12288;
    const int f    = rem >> 9;
    const int rem2 = rem & 511;
    const int l    = rem2 >> 3;
    const int j    = rem2 & 7;
    const int c    = w * 16 + (l & 15);
    const int ko   = (l >> 4) * 8 + j;
    float val;
    if (f < 8) {
        const int k = f * 32 + ko;
        val = (k < 128) ? W_ih[c * 128 + k] : W_hh[c * 128 + (k - 128)];
    } else if (f < 16) {
        const int k = (f - 8) * 32 + ko;
        val = (k < 128) ? W_ih[(128 + c) * 128 + k] : W_hh[(128 + c) * 128 + (k - 128)];
    } else if (f < 20) {
        const int k = (f - 16) * 32 + ko;
        val = W_ih[(256 + c) * 128 + k];
    } else {
        const int k = (f - 20 + 4) * 32 + ko;
        val = W_hh[(256 + c) * 128 + (k - 128)];
    }
    B[i] = f2bf_rne(val);
}

__global__ __launch_bounds__(256) void k_flag(const int* __restrict__ i_obs,
                                              unsigned char* __restrict__ flags, int n) {
    const int i = blockIdx.x * 256 + threadIdx.x;
    if (i < n) flags[i_obs[i]] = 1;
}

__global__ __launch_bounds__(256) void k_copy(const f32x4* __restrict__ src,
                                              f32x4* __restrict__ dst, long n4) {
    long i = (long)blockIdx.x * blockDim.x + threadIdx.x;
    long stride = (long)gridDim.x * blockDim.x;
    for (; i < n4; i += stride) dst[i] = src[i];
}

struct PrefRegs {
    float mean[4], lv[4], X[4], M[4];
    f32x4 hv[4];
    int idx[4];
};

__global__ __launch_bounds__(512, 2) void k_pers(
    const float* __restrict__ h, const float* __restrict__ p,
    const float* __restrict__ X_obs, const float* __restrict__ M_obs,
    const int* __restrict__ i_obs,
    const float* __restrict__ w_prep, const float* __restrict__ bias_prep,
    const unsigned short* __restrict__ Bpk,
    const float* __restrict__ b_ih, const float* __restrict__ b_hh,
    float* __restrict__ out_h, float* __restrict__ out_losses,
    const unsigned char* __restrict__ flags,
    int NT, int chunk, int Nh, int do_copy)
{
    __shared__ unsigned short sA[4 * 8 * 64 * 8];   // 32 KB
    __shared__ int sIdx[64];

    const int tid  = threadIdx.x;
    const int d    = tid & 31;
    const int wid  = tid >> 6;
    const int lane = tid & 63;
    const int cw   = wid * 16 + (lane & 15);

    // ---- resident constants ----
    float wp[16], bp[4];
    #pragma unroll
    for (int t = 0; t < 16; ++t) wp[t] = w_prep[d * 16 + t];
    #pragma unroll
    for (int t = 0; t < 4; ++t) bp[t] = bias_prep[d * 4 + t];

    bf16x8 breg[24];
    {
        const bf16x8* bsrc = reinterpret_cast<const bf16x8*>(Bpk) + wid * 1536;
        #pragma unroll
        for (int f = 0; f < 24; ++f) breg[f] = bsrc[f * 64 + lane];
    }
    const float bR  = b_ih[cw]       + b_hh[cw];
    const float bZ  = b_ih[128 + cw] + b_hh[128 + cw];
    const float bIN = b_ih[256 + cw];
    const float bHN = b_hh[256 + cw];

    // frag coords (prep channel d; h col4 d)
    const int ksA  = d >> 3;            // gi k-step
    const int l16  = ((d >> 1) & 3) * 16;
    const int j0   = (d & 1) * 4;
    // epilogue h_old coords (k = 128 + cw)
    const int ksE  = 4 + (cw >> 5);
    const int l16E = ((cw >> 3) & 3) * 16;
    const int jE   = cw & 7;

    const bf16x8* aptr = reinterpret_cast<const bf16x8*>(sA);

    PrefRegs R;

    // ---------- phase lambdas ----------
    auto G_load = [&](int t) {
        const int row0 = t * 64;
        #pragma unroll
        for (int ps = 0; ps < 4; ++ps) {
            const int r   = ps * 16 + (tid >> 5);
            const int idx = i_obs[row0 + r];
            R.idx[ps]  = idx;
            R.mean[ps] = p[(size_t)idx * 64 + d];
            R.lv[ps]   = p[(size_t)idx * 64 + 32 + d];
            R.X[ps]    = X_obs[(size_t)(row0 + r) * 32 + d];
            R.M[ps]    = M_obs[(size_t)(row0 + r) * 32 + d];
            R.hv[ps]   = *reinterpret_cast<const f32x4*>(h + (size_t)idx * 128 + d * 4);
        }
    };

    auto C_phase = [&](int t) {
        const int row0 = t * 64;
        #pragma unroll
        for (int ps = 0; ps < 4; ++ps) {
            const int r  = ps * 16 + (tid >> 5);
            const int mt = r >> 4;
            if (d == 0) sIdx[r] = R.idx[ps];
            const float lv      = fminf(fmaxf(R.lv[ps], -10.f), 10.f);
            const float inv_sig = __expf(-0.5f * lv);
            const float X = R.X[ps], M = R.M[ps], mean = R.mean[ps];
            const float err = fminf(fmaxf((X - mean) * inv_sig, -1e6f), 1e6f);
            out_losses[(size_t)(row0 + r) * 32 + d] =
                0.5f * ((err * err + lv + 1.8378770664093453f) * M);
            ushort4 u;
            float g0 = fmaf(X, wp[0], fmaf(mean, wp[4], fmaf(lv, wp[8],  fmaf(err, wp[12], bp[0]))));
            float g1 = fmaf(X, wp[1], fmaf(mean, wp[5], fmaf(lv, wp[9],  fmaf(err, wp[13], bp[1]))));
            float g2 = fmaf(X, wp[2], fmaf(mean, wp[6], fmaf(lv, wp[10], fmaf(err, wp[14], bp[2]))));
            float g3 = fmaf(X, wp[3], fmaf(mean, wp[7], fmaf(lv, wp[11], fmaf(err, wp[15], bp[3]))));
            u.x = f2bf_tr(fmaxf(g0, 0.f) * M);
            u.y = f2bf_tr(fmaxf(g1, 0.f) * M);
            u.z = f2bf_tr(fmaxf(g2, 0.f) * M);
            u.w = f2bf_tr(fmaxf(g3, 0.f) * M);
            *reinterpret_cast<ushort4*>(&sA[((mt * 8 + ksA) * 64 + (r & 15) + l16) * 8 + j0]) = u;
            const f32x4 v = R.hv[ps];
            ushort4 uh;
            uh.x = f2bf_tr(v.x); uh.y = f2bf_tr(v.y); uh.z = f2bf_tr(v.z); uh.w = f2bf_tr(v.w);
            *reinterpret_cast<ushort4*>(&sA[((mt * 8 + ksA + 4) * 64 + (r & 15) + l16) * 8 + j0]) = uh;
        }
    };

    auto M_phase = [&](int t) {
        #pragma unroll
        for (int mt = 0; mt < 4; ++mt) {
            f32x4 accR = {0.f, 0.f, 0.f, 0.f};
            f32x4 accZ = {0.f, 0.f, 0.f, 0.f};
            f32x4 accIN = {0.f, 0.f, 0.f, 0.f};
            f32x4 accHN = {0.f, 0.f, 0.f, 0.f};
            #pragma unroll
            for (int ks = 0; ks < 8; ++ks) {
                const bf16x8 af = aptr[(mt * 8 + ks) * 64 + lane];
                accR = __builtin_amdgcn_mfma_f32_16x16x32_bf16(af, breg[ks],     accR, 0, 0, 0);
                accZ = __builtin_amdgcn_mfma_f32_16x16x32_bf16(af, breg[8 + ks], accZ, 0, 0, 0);
                if (ks < 4) accIN = __builtin_amdgcn_mfma_f32_16x16x32_bf16(af, breg[16 + ks], accIN, 0, 0, 0);
                else        accHN = __builtin_amdgcn_mfma_f32_16x16x32_bf16(af, breg[16 + ks], accHN, 0, 0, 0);
            }
            const int r15b = (lane >> 4) * 4;
            #pragma unroll
            for (int reg = 0; reg < 4; ++reg) {
                const int r15 = r15b + reg;
                const int idx = sIdx[mt * 16 + r15];
                const float hp = bf2f(sA[((mt * 8 + ksE) * 64 + r15 + l16E) * 8 + jE]);
                const float xr  = accR[reg]  + bR;
                const float xz  = accZ[reg]  + bZ;
                const float xin = accIN[reg] + bIN;
                const float xhn = accHN[reg] + bHN;
                const float rg = fast_sigmoid(xr);
                const float zg = fast_sigmoid(xz);
                const float ng = fast_tanh(fmaf(rg, xhn, xin));
                out_h[(size_t)idx * 128 + cw] = fmaf(zg, hp - ng, ng);
            }
        }
    };

    auto COPY_phase = [&](int t) {
        const long rlo = (long)t * chunk;
        long rhi = rlo + chunk; if (rhi > Nh) rhi = Nh;
        const int nf4 = (int)((rhi - rlo) * 32);
        const f32x4* hs = reinterpret_cast<const f32x4*>(h + rlo * 128);
        f32x4*       hd = reinterpret_cast<f32x4*>(out_h + rlo * 128);
        const unsigned char* fl = flags + rlo;
        #pragma unroll
        for (int ii = 0; ii < 10; ++ii) {
            const int i5 = ii * 512 + tid;
            if (i5 < nf4) {
                const f32x4 v = hs[i5];
                if (!fl[i5 >> 5]) __builtin_nontemporal_store(v, &hd[i5]);
            }
        }
    };

    // ---------- persistent pipelined loop ----------
    int t = blockIdx.x;
    if (t >= NT) return;
    const int stride = gridDim.x;

    G_load(t);
    C_phase(t);
    __syncthreads();

    for (;;) {
        const int tn = t + stride;
        const bool has_next = (tn < NT);
        if (has_next) G_load(tn);       // next-tile gathers fly under M+COPY
        M_phase(t);
        if (do_copy) COPY_phase(t);
        __syncthreads();                // M's LDS reads complete
        if (!has_next) break;
        C_phase(tn);                    // overwrite LDS for next tile
        __syncthreads();
        t = tn;
    }
}

extern "C" void kernel_launch(void* const* d_in, const int* in_sizes, int n_in,
                              void* d_out, int out_size, void* d_ws, size_t ws_size,
                              hipStream_t stream) {
    const float* h         = (const float*)d_in[0];
    const float* p         = (const float*)d_in[1];
    const float* X_obs     = (const float*)d_in[2];
    const float* M_obs     = (const float*)d_in[3];
    const int*   i_obs     = (const int*)d_in[4];
    const float* w_prep    = (const float*)d_in[5];
    const float* bias_prep = (const float*)d_in[6];
    const float* W_ih      = (const float*)d_in[7];
    const float* W_hh      = (const float*)d_in[8];
    const float* b_ih      = (const float*)d_in[9];
    const float* b_hh      = (const float*)d_in[10];

    const int Nh   = in_sizes[0] / 128;   // 500000
    const int NOBS = in_sizes[4];         // 200000
    const int NT   = NOBS / 64;           // 3125 tiles
    const long n4  = (long)Nh * 128 / 4;

    float* out_h      = (float*)d_out;
    float* out_losses = out_h + (size_t)Nh * 128;

    unsigned short* Bpk   = (unsigned short*)d_ws;               // 192 KB
    unsigned char*  flags = (unsigned char*)d_ws + (256 << 10);  // Nh bytes
    const size_t ws_needed = (256 << 10) + (size_t)Nh;

    hipLaunchKernelGGL(k_prepack, dim3(98304 / 256), dim3(256), 0, stream,
                       W_ih, W_hh, Bpk);

    const int chunk = (Nh + NT - 1) / NT;    // 160 -> 5120 f4 = 10 passes of 512
    const int GRID  = 512;

    if (ws_size >= ws_needed && chunk <= 160) {
        (void)hipMemsetAsync(flags, 0, (size_t)Nh, stream);
        hipLaunchKernelGGL(k_flag, dim3((NOBS + 255) / 256), dim3(256), 0, stream,
                           i_obs, flags, NOBS);
        hipLaunchKernelGGL(k_pers, dim3(GRID), dim3(512), 0, stream,
                           h, p, X_obs, M_obs, i_obs, w_prep, bias_prep, Bpk,
                           b_ih, b_hh, out_h, out_losses, flags, NT, chunk, Nh, 1);
    } else {
        hipLaunchKernelGGL(k_copy, dim3(4096), dim3(256), 0, stream,
                           (const f32x4*)h, (f32x4*)out_h, n4);
        hipLaunchKernelGGL(k_pers, dim3(GRID), dim3(512), 0, stream,
                           h, p, X_obs, M_obs, i_obs, w_prep, bias_prep, Bpk,
                           b_ih, b_hh, out_h, out_losses,
                           (const unsigned char*)nullptr, NT, chunk, Nh, 0);
    }
}